// Round 3
// baseline (377.059 us; speedup 1.0000x reference)
//
#include <hip/hip_runtime.h>

typedef __bf16 bf16;
typedef unsigned int u32;
typedef float f32x4 __attribute__((ext_vector_type(4)));
typedef __bf16 bf16x4 __attribute__((ext_vector_type(4)));
typedef __bf16 bf16x8 __attribute__((ext_vector_type(8)));

#define MFMA(a, b, c) __builtin_amdgcn_mfma_f32_16x16x32_bf16((a), (b), (c), 0, 0, 0)

static constexpr int Bc = 4;      // batch
static constexpr int Sc = 2048;   // seq len
static constexpr int Hc = 16;     // heads
static constexpr int DHc = 64;    // head dim
static constexpr int Dc = 1024;   // model dim
static constexpr int Mc = Bc * Sc; // 8192 rows

// async 16B/lane global->LDS. lp must be wave-uniform; lane i lands at lp+16*i.
__device__ __forceinline__ void load_lds16(const bf16* gp, bf16* lp) {
    __builtin_amdgcn_global_load_lds(
        reinterpret_cast<const __attribute__((address_space(1))) u32*>(
            reinterpret_cast<uintptr_t>(gp)),
        reinterpret_cast<__attribute__((address_space(3))) u32*>(
            static_cast<u32>(reinterpret_cast<uintptr_t>(lp))),
        16, 0, 0);
}

// ---------------------------------------------------------------------------
__global__ void fill_diag(float* out, int n) {
    int i = blockIdx.x * 256 + threadIdx.x;
    if (i < n) out[i] = 1000.0f;
}

// ---------------------------------------------------------------------------
// 4x fused 1024x1024 transpose + fp32->bf16: Oi[n][k] = (bf16)Ai[k][n]
// ---------------------------------------------------------------------------
__global__ __launch_bounds__(256) void transpose4(
    const float* __restrict__ A0, const float* __restrict__ A1,
    const float* __restrict__ A2, const float* __restrict__ A3,
    bf16* __restrict__ O0, bf16* __restrict__ O1,
    bf16* __restrict__ O2, bf16* __restrict__ O3) {
    __shared__ bf16 t[32][33];
    const float* in = blockIdx.z == 0 ? A0 : blockIdx.z == 1 ? A1
                    : blockIdx.z == 2 ? A2 : A3;
    bf16* out = blockIdx.z == 0 ? O0 : blockIdx.z == 1 ? O1
              : blockIdx.z == 2 ? O2 : O3;
    int x = blockIdx.x * 32 + threadIdx.x;
#pragma unroll
    for (int j = 0; j < 32; j += 8) {
        int y = blockIdx.y * 32 + threadIdx.y + j;
        t[threadIdx.y + j][threadIdx.x] = (bf16)in[y * 1024 + x];
    }
    __syncthreads();
    int x2 = blockIdx.y * 32 + threadIdx.x;
#pragma unroll
    for (int j = 0; j < 32; j += 8) {
        int y2 = blockIdx.x * 32 + threadIdx.y + j;
        out[y2 * 1024 + x2] = t[threadIdx.x][threadIdx.y + j];
    }
}

// ---------------------------------------------------------------------------
// Fused QKV projection: 3 GEMMs (grid.z selects), A read as FP32 directly
// (conversion fused into staging -> cvt_bf16 passes + Xin buffer deleted).
// A staged in k-chunk-major LDS layout As[c][row][8] so the reg-staged
// ds_write_b128 spreads 8-way-even (the b128 bank floor); B stays
// global_load_lds DMA. z=0,1 -> [B,H,S,Dh] out; z=2 -> [B,H,Dh,S].
// ---------------------------------------------------------------------------
__global__ __launch_bounds__(256) void gemm_qkv(
    const float* __restrict__ Aq, const float* __restrict__ Ak,
    const float* __restrict__ Av,
    const bf16* __restrict__ Wq, const bf16* __restrict__ Wk,
    const bf16* __restrict__ Wv,
    const float* __restrict__ bq, const float* __restrict__ bk,
    const float* __restrict__ bv,
    bf16* __restrict__ Oq, bf16* __restrict__ Ok, bf16* __restrict__ Ov) {
    __shared__ alignas(16) bf16 As[4 * 128 * 8];  // [c][row][8], c = k/8
    __shared__ alignas(16) bf16 Bs[128 * 32];
    const int z = blockIdx.z;
    const float* A = z == 0 ? Aq : z == 1 ? Ak : Av;
    const bf16* Wt = z == 0 ? Wq : z == 1 ? Wk : Wv;
    const float* bias = z == 0 ? bq : z == 1 ? bk : bv;
    bf16* out = z == 0 ? Oq : z == 1 ? Ok : Ov;
    const bool vmode = (z == 2);

    const int tid = threadIdx.x;
    const int wave = tid >> 6, lane = tid & 63;
    const int quad = lane >> 4, l16 = lane & 15;
    const int wr = (wave >> 1) * 64, wc = (wave & 1) * 64;
    const int id = blockIdx.y * 8 + blockIdx.x;       // bijective XCD swizzle
    const int sw = (id & 7) * 64 + (id >> 3);
    const int row0 = (sw >> 3) * 128, col0 = (sw & 7) * 128;

    // A staging: thread covers row rw, two 8-elem k-chunks ce, ce+1
    const int rw = wave * 32 + (lane >> 1);
    const int ce = (lane & 1) * 2;
    const float* gA = &A[(size_t)(row0 + rw) * Dc + ce * 8];
    // B staging (DMA, unchanged layout [128][32])
    const int sr = wave * 32 + (lane >> 2);
    const int sk = (lane & 3) * 8;
    const bf16* gB = &Wt[(size_t)(col0 + sr) * Dc + sk];
    bf16* lB = &Bs[wave * 32 * 32];

    f32x4 acc[4][4];
#pragma unroll
    for (int mi = 0; mi < 4; ++mi)
#pragma unroll
        for (int ni = 0; ni < 4; ++ni)
            acc[mi][ni] = (f32x4){0.f, 0.f, 0.f, 0.f};

    for (int k0 = 0; k0 < Dc; k0 += 32) {
        __syncthreads();
        f32x4 a0 = *(const f32x4*)(gA + k0);
        f32x4 a1 = *(const f32x4*)(gA + k0 + 4);
        f32x4 a2 = *(const f32x4*)(gA + k0 + 8);
        f32x4 a3 = *(const f32x4*)(gA + k0 + 12);
        load_lds16(gB + k0, lB);
        load_lds16(gB + k0 + 16 * Dc, lB + 16 * 32);
        bf16x8 v0, v1;
#pragma unroll
        for (int j = 0; j < 4; ++j) {
            v0[j] = (bf16)a0[j]; v0[j + 4] = (bf16)a1[j];
            v1[j] = (bf16)a2[j]; v1[j + 4] = (bf16)a3[j];
        }
        *(bf16x8*)&As[ce * 1024 + rw * 8] = v0;
        *(bf16x8*)&As[(ce + 1) * 1024 + rw * 8] = v1;
        __syncthreads();   // drains B DMA (vmcnt) + As writes (lgkm)

        bf16x8 af[4], bf_[4];
#pragma unroll
        for (int mi = 0; mi < 4; ++mi)
            af[mi] = *(const bf16x8*)&As[quad * 1024 + (wr + mi * 16 + l16) * 8];
#pragma unroll
        for (int ni = 0; ni < 4; ++ni)
            bf_[ni] = *(const bf16x8*)&Bs[(wc + ni * 16 + l16) * 32 + quad * 8];
#pragma unroll
        for (int mi = 0; mi < 4; ++mi)
#pragma unroll
            for (int ni = 0; ni < 4; ++ni)
                acc[mi][ni] = MFMA(af[mi], bf_[ni], acc[mi][ni]);
    }

    // epilogue: C/D layout col=lane&15, row=quad*4+reg
#pragma unroll
    for (int mi = 0; mi < 4; ++mi) {
#pragma unroll
        for (int ni = 0; ni < 4; ++ni) {
            int col = col0 + wc + ni * 16 + l16;
            float bv = bias[col];
#pragma unroll
            for (int r = 0; r < 4; ++r) {
                int row = row0 + wr + mi * 16 + quad * 4 + r;
                float v = acc[mi][ni][r] + bv;
                int b = row >> 11, s = row & (Sc - 1);
                int h = col >> 6, dh = col & (DHc - 1);
                size_t off;
                if (!vmode)
                    off = (((size_t)(b * Hc + h) * Sc + s) << 6) + dh;
                else
                    off = (((size_t)(b * Hc + h) * DHc + dh) << 11) + s;
                out[off] = (bf16)v;
            }
        }
    }
}

// ---------------------------------------------------------------------------
// C[M,N] = A[M,K] @ Wt[N,K]^T + bias[N]; bf16 A via DMA; fp32 out row-major.
// (output projection only)
// ---------------------------------------------------------------------------
__global__ __launch_bounds__(256) void gemm_bt(const bf16* __restrict__ A,
                                               const bf16* __restrict__ Wt,
                                               const float* __restrict__ bias,
                                               float* __restrict__ out,
                                               int M, int N, int K) {
    __shared__ alignas(16) bf16 As[128 * 32];
    __shared__ alignas(16) bf16 Bs[128 * 32];
    const int tid = threadIdx.x;
    const int wave = tid >> 6, lane = tid & 63;
    const int quad = lane >> 4, l16 = lane & 15;
    const int wr = (wave >> 1) * 64, wc = (wave & 1) * 64;
    const int id = blockIdx.y * 8 + blockIdx.x;
    const int sw = (id & 7) * 64 + (id >> 3);
    const int row0 = (sw >> 3) * 128, col0 = (sw & 7) * 128;

    const int sr = wave * 32 + (lane >> 2);
    const int sk = (lane & 3) * 8;
    const bf16* gA = &A[(size_t)(row0 + sr) * K + sk];
    const bf16* gB = &Wt[(size_t)(col0 + sr) * K + sk];
    bf16* lA = &As[wave * 32 * 32];
    bf16* lB = &Bs[wave * 32 * 32];

    f32x4 acc[4][4];
#pragma unroll
    for (int mi = 0; mi < 4; ++mi)
#pragma unroll
        for (int ni = 0; ni < 4; ++ni)
            acc[mi][ni] = (f32x4){0.f, 0.f, 0.f, 0.f};

    for (int k0 = 0; k0 < K; k0 += 32) {
        __syncthreads();
        load_lds16(gA + k0, lA);
        load_lds16(gA + k0 + 16 * K, lA + 16 * 32);
        load_lds16(gB + k0, lB);
        load_lds16(gB + k0 + 16 * K, lB + 16 * 32);
        __syncthreads();

        bf16x8 af[4], bf_[4];
#pragma unroll
        for (int mi = 0; mi < 4; ++mi)
            af[mi] = *(const bf16x8*)&As[(wr + mi * 16 + l16) * 32 + quad * 8];
#pragma unroll
        for (int ni = 0; ni < 4; ++ni)
            bf_[ni] = *(const bf16x8*)&Bs[(wc + ni * 16 + l16) * 32 + quad * 8];
#pragma unroll
        for (int mi = 0; mi < 4; ++mi)
#pragma unroll
            for (int ni = 0; ni < 4; ++ni)
                acc[mi][ni] = MFMA(af[mi], bf_[ni], acc[mi][ni]);
    }

#pragma unroll
    for (int mi = 0; mi < 4; ++mi) {
#pragma unroll
        for (int ni = 0; ni < 4; ++ni) {
            int col = col0 + wc + ni * 16 + l16;
            float bv = bias[col];
#pragma unroll
            for (int r = 0; r < 4; ++r) {
                int row = row0 + wr + mi * 16 + quad * 4 + r;
                out[(size_t)row * N + col] = acc[mi][ni][r] + bv;
            }
        }
    }
}

// ---------------------------------------------------------------------------
// Flash-style causal attention, v6: v5 pipeline + 3 blocks/CU occupancy.
// v5 post-mortem: 64us, Occupancy 17.9% (2 blocks/CU, LDS-capped at 59.4KB),
// latency bubbles in the barrier-locked QK->softmax->PV chain. v6:
//  - LDS 59.4KB -> 48.5KB => 3 blocks/CU:
//      Ps: unpadded 128B rows + same XOR-granule swizzle as K/V
//          (write g=kti*2+(quad>>1) ^ (row&7); read g=kk*4+quad ^ (row&7);
//           element-traced for consistency),
//      msk: [2][64] staged per-tile via 1-VGPR register pipeline (load for
//           tile t+2 while writing t+1) instead of an 8KB whole-row buffer.
//  - 1024 single-q-tile blocks (heavy-first, XCD-chunked: 8 bh per XCD =
//    4MB K/V = L2); 4 blocks/CU of work over 3 resident slots self-balances.
//  - barrier asm now drains lgkmcnt too (msk ds_write crosses waves).
// Q,K: [B,H,S,Dh] bf16; Vt: [B,H,Dh,S] bf16; mask: [B,S] int32
// ---------------------------------------------------------------------------
static constexpr float CEXP = 1.4426950408889634f / 4096.0f; // log2(e)/Dh^2

__global__ __launch_bounds__(256, 3) void attn_fwd(const bf16* __restrict__ Q,
                                                   const bf16* __restrict__ K,
                                                   const bf16* __restrict__ Vt,
                                                   const int* __restrict__ mask,
                                                   bf16* __restrict__ Ctx) {
    __shared__ alignas(16) bf16 Ks[2][64 * 64];   // [buf][row*64+g*8] swizzled
    __shared__ alignas(16) bf16 Vs[2][64 * 64];   // [buf][dh*64+g*8] swizzled
    __shared__ alignas(16) bf16 Ps[4][32 * 64];   // per-wave P, swizzled
    __shared__ alignas(16) float msk[2][64];      // per-tile pad mask (dbuf)

    const int tid = threadIdx.x;
    const int wave = tid >> 6, lane = tid & 63;
    const int quad = lane >> 4, l16 = lane & 15;
    // grid (16,64) = 1024 blocks; XCD chunk 128 -> bh [8k,8k+8) per XCD,
    // qt = 15..0 (heavy-first) within each bh.
    const int id = blockIdx.y * 16 + blockIdx.x;
    const int sw = (id & 7) * 128 + (id >> 3);
    const int bh = sw >> 4, b = bh >> 4, h = bh & 15;
    const int qt = 15 - (sw & 15);
    const int qr0 = qt * 128 + wave * 32;
    const int qmax = qr0 + 31;

    // ---- staging geometry (both-sides swizzle, rule #21)
    const int swz = ((lane & 7) ^ (lane >> 3)) << 4;   // source byte XOR
    const int rA = wave * 16 + (lane >> 3);            // local row, j=0
    const char* gK0 = (const char*)K + (size_t)bh * Sc * (DHc * 2)
                    + (size_t)rA * 128 + swz;
    const char* gV0 = (const char*)Vt + (size_t)bh * DHc * (Sc * 2)
                    + (size_t)rA * (Sc * 2) + swz;
    bf16* lK0 = &Ks[0][(wave * 16) * 64];
    bf16* lV0 = &Vs[0][(wave * 16) * 64];

    // read-side swizzled granule offsets (elements)
    const int m7 = l16 & 7;
    const int gsw0 = ((0 + quad) ^ m7) * 8;
    const int gsw1 = ((4 + quad) ^ m7) * 8;

#define STAGE(BUF, KB)                                                        \
    do {                                                                      \
        load_lds16((const bf16*)(gK0 + (size_t)(KB) * 128),                   \
                   lK0 + (BUF) * (64 * 64));                                  \
        load_lds16((const bf16*)(gK0 + (size_t)(KB) * 128 + 1024),            \
                   lK0 + (BUF) * (64 * 64) + 8 * 64);                         \
        load_lds16((const bf16*)(gV0 + (size_t)(KB) * 2),                     \
                   lV0 + (BUF) * (64 * 64));                                  \
        load_lds16((const bf16*)(gV0 + (size_t)(KB) * 2 + 8 * 4096),          \
                   lV0 + (BUF) * (64 * 64) + 8 * 64);                         \
    } while (0)

    // Q fragments (B-operand of S^T): n=q=l16, k=dh=quad*8+j
    bf16x8 bq[2][2];
#pragma unroll
    for (int mt = 0; mt < 2; ++mt) {
        const size_t qoff = ((size_t)bh * Sc + qr0 + mt * 16 + l16) * DHc;
        bq[mt][0] = *(const bf16x8*)&Q[qoff + quad * 8];
        bq[mt][1] = *(const bf16x8*)&Q[qoff + 32 + quad * 8];
    }

    f32x4 accO[2][4];
#pragma unroll
    for (int mt = 0; mt < 2; ++mt)
#pragma unroll
        for (int oi = 0; oi < 4; ++oi) accO[mt][oi] = (f32x4){0.f, 0.f, 0.f, 0.f};
    float l_part[2] = {0.f, 0.f};

    const int nkt = 2 * qt + 2;                  // causal: k-tiles 0..(2qt+1)
    int mreg = 1;
    if (tid < 64) {
        msk[0][tid] = mask[b * Sc + tid] ? 0.f : -1e30f;
        mreg = mask[b * Sc + 64 + tid];          // for tile 1 (always exists)
    }
    STAGE(0, 0);
    __syncthreads();                             // tile 0 + msk[0] ready
    int cur = 0;
#pragma unroll 1
    for (int kt = 0; kt < nkt; ++kt) {
        const int kb = kt * 64;
        if (kt + 1 < nkt) {
            STAGE(cur ^ 1, kb + 64);             // issue next tile DMA
            if (tid < 64) {
                msk[cur ^ 1][tid] = mreg ? 0.f : -1e30f;
                mreg = mask[b * Sc + ((kb + 128 + tid) & (Sc - 1))]; // t+2
            }
        }
        if (kb <= qmax) {                        // wave-uniform skip
            const bf16* Kb_ = &Ks[cur][0];
            const bf16* Vb_ = &Vs[cur][0];

            // S^T = K Q^T : A-frag = K rows (m=key), B-frag = bq (n=q)
            f32x4 st[2][4];
            __builtin_amdgcn_s_setprio(1);
#pragma unroll
            for (int kti = 0; kti < 4; ++kti) {
                bf16x8 ak0 = *(const bf16x8*)&Kb_[(kti * 16 + l16) * 64 + gsw0];
                bf16x8 ak1 = *(const bf16x8*)&Kb_[(kti * 16 + l16) * 64 + gsw1];
#pragma unroll
                for (int mt = 0; mt < 2; ++mt) {
                    f32x4 z = {0.f, 0.f, 0.f, 0.f};
                    z = MFMA(ak0, bq[mt][0], z);
                    z = MFMA(ak1, bq[mt][1], z);
                    st[mt][kti] = z;
                }
            }
            __builtin_amdgcn_s_setprio(0);

            // softmax numerator in exp2 domain; swizzled packed P store
#define SM_TILE(DIAG)                                                          \
            _Pragma("unroll")                                                  \
            for (int mt = 0; mt < 2; ++mt) {                                   \
                _Pragma("unroll")                                              \
                for (int kti = 0; kti < 4; ++kti) {                            \
                    const f32x4 mkv =                                          \
                        *(const f32x4*)&msk[cur][kti * 16 + quad * 4];         \
                    const int cbase =                                          \
                        kb + kti * 16 + quad * 4 - (qr0 + mt * 16);            \
                    bf16x4 pv;                                                 \
                    _Pragma("unroll")                                          \
                    for (int r = 0; r < 4; ++r) {                              \
                        float s = st[mt][kti][r] * CEXP + mkv[r];              \
                        if (DIAG) s = (cbase + r > l16) ? -1e30f : s;          \
                        float p_ = __builtin_amdgcn_exp2f(s);                  \
                        l_part[mt] += p_;                                      \
                        pv[r] = (bf16)p_;                                      \
                    }                                                          \
                    *(bf16x4*)&Ps[wave][(mt * 16 + l16) * 64 +                 \
                        (((kti * 2 + (quad >> 1)) ^ m7) * 8) +                 \
                        (quad & 1) * 4] = pv;                                  \
                }                                                              \
            }
            if (kb + 63 > qr0) { SM_TILE(1) } else { SM_TILE(0) }
#undef SM_TILE
            // Ps[wave] wave-private: per-wave DS ordering suffices

            // O += P V : A = Ps rows (m=q), B = Vs rows (n=dh)
            __builtin_amdgcn_s_setprio(1);
#pragma unroll
            for (int kk = 0; kk < 2; ++kk) {
                const int pg = ((kk * 4 + quad) ^ m7) * 8;
                bf16x8 ap0 = *(const bf16x8*)&Ps[wave][(l16) * 64 + pg];
                bf16x8 ap1 = *(const bf16x8*)&Ps[wave][(16 + l16) * 64 + pg];
                const int vg = kk ? gsw1 : gsw0;
#pragma unroll
                for (int oi = 0; oi < 4; ++oi) {
                    bf16x8 bv = *(const bf16x8*)&Vb_[(oi * 16 + l16) * 64 + vg];
                    accO[0][oi] = MFMA(ap0, bv, accO[0][oi]);
                    accO[1][oi] = MFMA(ap1, bv, accO[1][oi]);
                }
            }
            __builtin_amdgcn_s_setprio(0);
        }
        // wait own DMA + msk ds_write, publish across waves
        asm volatile("s_waitcnt vmcnt(0) lgkmcnt(0)" ::: "memory");
        __builtin_amdgcn_s_barrier();
        __builtin_amdgcn_sched_barrier(0);
        cur ^= 1;
    }
#undef STAGE

    // epilogue: finish l (sum over quads), redistribute, store
    float lvi[2][4];
#pragma unroll
    for (int mt = 0; mt < 2; ++mt) {
        float l = l_part[mt];
        l += __shfl_xor(l, 16);
        l += __shfl_xor(l, 32);                  // lane holds l for q=l16
#pragma unroll
        for (int r = 0; r < 4; ++r)
            lvi[mt][r] = __builtin_amdgcn_rcpf(__shfl(l, quad * 4 + r));
    }
#pragma unroll
    for (int mt = 0; mt < 2; ++mt)
#pragma unroll
        for (int oi = 0; oi < 4; ++oi)
#pragma unroll
            for (int r = 0; r < 4; ++r) {
                int s = qr0 + mt * 16 + quad * 4 + r;
                int dh = oi * 16 + l16;
                float v = accO[mt][oi][r] * lvi[mt][r];
                Ctx[((size_t)b * Sc + s) * Dc + h * DHc + dh] = (bf16)v;
            }
}

// ---------------------------------------------------------------------------
extern "C" void kernel_launch(void* const* d_in, const int* in_sizes, int n_in,
                              void* d_out, int out_size, void* d_ws, size_t ws_size,
                              hipStream_t stream) {
    const float* query = (const float*)d_in[0];
    const float* key_i = (const float*)d_in[1];
    const float* value = (const float*)d_in[2];
    const int* mask    = (const int*)d_in[3];
    const float* W_q = (const float*)d_in[4];
    const float* b_q = (const float*)d_in[5];
    const float* W_k = (const float*)d_in[6];
    const float* b_k = (const float*)d_in[7];
    const float* W_v = (const float*)d_in[8];
    const float* b_v = (const float*)d_in[9];
    const float* W_o = (const float*)d_in[10];
    const float* b_o = (const float*)d_in[11];
    float* out = (float*)d_out;

    const size_t MB = 1024 * 1024;
    const size_t NEED = 72 * MB;
    if (ws_size < NEED) {
        fill_diag<<<(out_size + 255) / 256, 256, 0, stream>>>(out, out_size);
        return;
    }

    char* ws = (char*)d_ws;
    bf16* WtQ = (bf16*)(ws + 0 * MB);   // 2 MB each
    bf16* WtK = (bf16*)(ws + 2 * MB);
    bf16* WtV = (bf16*)(ws + 4 * MB);
    bf16* WtO = (bf16*)(ws + 6 * MB);
    bf16* Qb  = (bf16*)(ws + 8 * MB);   // [B,H,S,Dh]  16 MB
    bf16* Kb  = (bf16*)(ws + 24 * MB);  // [B,H,S,Dh]  16 MB
    bf16* Vtb = (bf16*)(ws + 40 * MB);  // [B,H,Dh,S]  16 MB
    bf16* Ctx = (bf16*)(ws + 56 * MB);  // [B,S,D]     16 MB

    transpose4<<<dim3(32, 32, 4), dim3(32, 8), 0, stream>>>(
        W_q, W_k, W_v, W_o, WtQ, WtK, WtV, WtO);

    gemm_qkv<<<dim3(8, 64, 3), 256, 0, stream>>>(
        query, key_i, value, WtQ, WtK, WtV, b_q, b_k, b_v, Qb, Kb, Vtb);

    attn_fwd<<<dim3(16, 64), 256, 0, stream>>>(Qb, Kb, Vtb, mask, Ctx);

    gemm_bt<<<dim3(8, 64), 256, 0, stream>>>(Ctx, WtO, b_o, out, Mc, Dc, Dc);
}

// Round 4
// 319.606 us; speedup vs baseline: 1.1798x; 1.1798x over previous
//
#include <hip/hip_runtime.h>

typedef __bf16 bf16;
typedef unsigned int u32;
typedef float f32x4 __attribute__((ext_vector_type(4)));
typedef __bf16 bf16x4 __attribute__((ext_vector_type(4)));
typedef __bf16 bf16x8 __attribute__((ext_vector_type(8)));

#define MFMA(a, b, c) __builtin_amdgcn_mfma_f32_16x16x32_bf16((a), (b), (c), 0, 0, 0)

static constexpr int Bc = 4;      // batch
static constexpr int Sc = 2048;   // seq len
static constexpr int Hc = 16;     // heads
static constexpr int DHc = 64;    // head dim
static constexpr int Dc = 1024;   // model dim
static constexpr int Mc = Bc * Sc; // 8192 rows

// async 16B/lane global->LDS. lp must be wave-uniform; lane i lands at lp+16*i.
__device__ __forceinline__ void load_lds16(const bf16* gp, bf16* lp) {
    __builtin_amdgcn_global_load_lds(
        reinterpret_cast<const __attribute__((address_space(1))) u32*>(
            reinterpret_cast<uintptr_t>(gp)),
        reinterpret_cast<__attribute__((address_space(3))) u32*>(
            static_cast<u32>(reinterpret_cast<uintptr_t>(lp))),
        16, 0, 0);
}

// ---------------------------------------------------------------------------
__global__ void fill_diag(float* out, int n) {
    int i = blockIdx.x * 256 + threadIdx.x;
    if (i < n) out[i] = 1000.0f;
}

// ---------------------------------------------------------------------------
// fp32 -> bf16 bulk convert (8 elems/thread). (Round-3 lesson: fusing this
// into the GEMM as synchronous fp32 reg-staging exposed HBM latency every
// k-step and cost more than the extra pass. DMA staging needs bf16 input.)
// ---------------------------------------------------------------------------
__global__ __launch_bounds__(256) void cvt_bf16(const float* __restrict__ in,
                                                bf16* __restrict__ out, int n) {
    int i = (blockIdx.x * 256 + threadIdx.x) * 8;
    if (i < n) {
        f32x4 a = *(const f32x4*)&in[i];
        f32x4 b = *(const f32x4*)&in[i + 4];
        bf16x8 v;
#pragma unroll
        for (int j = 0; j < 4; ++j) { v[j] = (bf16)a[j]; v[j + 4] = (bf16)b[j]; }
        *(bf16x8*)&out[i] = v;
    }
}

// ---------------------------------------------------------------------------
// 4x fused 1024x1024 transpose + fp32->bf16: Oi[n][k] = (bf16)Ai[k][n]
// ---------------------------------------------------------------------------
__global__ __launch_bounds__(256) void transpose4(
    const float* __restrict__ A0, const float* __restrict__ A1,
    const float* __restrict__ A2, const float* __restrict__ A3,
    bf16* __restrict__ O0, bf16* __restrict__ O1,
    bf16* __restrict__ O2, bf16* __restrict__ O3) {
    __shared__ bf16 t[32][33];
    const float* in = blockIdx.z == 0 ? A0 : blockIdx.z == 1 ? A1
                    : blockIdx.z == 2 ? A2 : A3;
    bf16* out = blockIdx.z == 0 ? O0 : blockIdx.z == 1 ? O1
              : blockIdx.z == 2 ? O2 : O3;
    int x = blockIdx.x * 32 + threadIdx.x;
#pragma unroll
    for (int j = 0; j < 32; j += 8) {
        int y = blockIdx.y * 32 + threadIdx.y + j;
        t[threadIdx.y + j][threadIdx.x] = (bf16)in[y * 1024 + x];
    }
    __syncthreads();
    int x2 = blockIdx.y * 32 + threadIdx.x;
#pragma unroll
    for (int j = 0; j < 32; j += 8) {
        int y2 = blockIdx.x * 32 + threadIdx.y + j;
        out[y2 * 1024 + x2] = t[threadIdx.x][threadIdx.y + j];
    }
}

// ---------------------------------------------------------------------------
// C[M,N] = A[M,K] @ Wt[N,K]^T + bias[N]; bf16 in, fp32 accum, TOUT out.
// v4 GEMM: m97 tile + XCD swizzle + T3/T4 counted-vmcnt 3-buffer pipeline.
// Round-3 diagnosis: 2-barrier full-drain structure is latency-bound at this
// shape (MfmaUtil 13.5%, HBM 11%): every k-step waits the whole DMA.
// Pipeline: prologue stages tiles 0,1; iter i issues STAGE(i+2), computes
// tile i, then s_waitcnt vmcnt(4) -> stage i+1 stays IN FLIGHT across the
// barrier (T4: never drain to 0 in the main loop; each DMA gets ~2 iters).
// Buffer hazard: iter i writes buf (i+2)%3, last read in iter i-1 before its
// end-of-iter barrier -> safe.
// MODE 0: out row-major [M,N]; MODE 1: [B,H,S,Dh]; MODE 2: [B,H,Dh,S]
// ---------------------------------------------------------------------------
template <int MODE, typename TOUT>
__global__ __launch_bounds__(256) void gemm_bt(const bf16* __restrict__ A,
                                               const bf16* __restrict__ Wt,
                                               const float* __restrict__ bias,
                                               TOUT* __restrict__ out,
                                               int M, int N, int K) {
    __shared__ alignas(16) bf16 As[3][128 * 32];
    __shared__ alignas(16) bf16 Bs[3][128 * 32];
    const int tid = threadIdx.x;
    const int wave = tid >> 6, lane = tid & 63;
    const int quad = lane >> 4, l16 = lane & 15;
    const int wr = (wave >> 1) * 64, wc = (wave & 1) * 64;
    const int id = blockIdx.y * 8 + blockIdx.x;       // bijective XCD swizzle
    const int sw = (id & 7) * 64 + (id >> 3);
    const int row0 = (sw >> 3) * 128, col0 = (sw & 7) * 128;

    // staging: wave covers rows [wave*32, wave*32+32); lane i -> 16B chunk
    const int sr = wave * 32 + (lane >> 2);
    const int sk = (lane & 3) * 8;
    const bf16* gA = &A[(size_t)(row0 + sr) * K + sk];
    const bf16* gB = &Wt[(size_t)(col0 + sr) * K + sk];
    const int wo = wave * 32 * 32;   // wave's slice offset within one buffer

#define GSTAGE(BUF, KOFF)                                                   \
    do {                                                                    \
        load_lds16(gA + (KOFF), &As[BUF][wo]);                              \
        load_lds16(gA + (KOFF) + 16 * K, &As[BUF][wo + 16 * 32]);           \
        load_lds16(gB + (KOFF), &Bs[BUF][wo]);                              \
        load_lds16(gB + (KOFF) + 16 * K, &Bs[BUF][wo + 16 * 32]);           \
    } while (0)

    f32x4 acc[4][4];
#pragma unroll
    for (int mi = 0; mi < 4; ++mi)
#pragma unroll
        for (int ni = 0; ni < 4; ++ni)
            acc[mi][ni] = (f32x4){0.f, 0.f, 0.f, 0.f};

    const int nk = K / 32;                // 32 for all our GEMMs
    GSTAGE(0, 0);
    GSTAGE(1, 32);
    asm volatile("s_waitcnt vmcnt(4)" ::: "memory");  // stage 0 done
    __builtin_amdgcn_s_barrier();                     // visible to all waves
    __builtin_amdgcn_sched_barrier(0);

    int cur = 0, nxt = 2;
#pragma unroll 1
    for (int i = 0; i < nk; ++i) {
        if (i + 2 < nk) GSTAGE(nxt, (i + 2) * 32);    // deep prefetch

        bf16x8 af[4], bf_[4];
#pragma unroll
        for (int mi = 0; mi < 4; ++mi)
            af[mi] = *(const bf16x8*)&As[cur][(wr + mi * 16 + l16) * 32 + quad * 8];
#pragma unroll
        for (int ni = 0; ni < 4; ++ni)
            bf_[ni] = *(const bf16x8*)&Bs[cur][(wc + ni * 16 + l16) * 32 + quad * 8];
#pragma unroll
        for (int mi = 0; mi < 4; ++mi)
#pragma unroll
            for (int ni = 0; ni < 4; ++ni)
                acc[mi][ni] = MFMA(af[mi], bf_[ni], acc[mi][ni]);

        // stage i+1 must be done for next iter; stage i+2 stays in flight
        if (i + 2 < nk) asm volatile("s_waitcnt vmcnt(4)" ::: "memory");
        else            asm volatile("s_waitcnt vmcnt(0)" ::: "memory");
        __builtin_amdgcn_s_barrier();
        __builtin_amdgcn_sched_barrier(0);
        cur = (cur == 2) ? 0 : cur + 1;
        nxt = (nxt == 2) ? 0 : nxt + 1;
    }
#undef GSTAGE

    // epilogue: C/D layout col=lane&15, row=quad*4+reg
#pragma unroll
    for (int mi = 0; mi < 4; ++mi) {
#pragma unroll
        for (int ni = 0; ni < 4; ++ni) {
            int col = col0 + wc + ni * 16 + l16;
            float bv = bias[col];
#pragma unroll
            for (int r = 0; r < 4; ++r) {
                int row = row0 + wr + mi * 16 + quad * 4 + r;
                float v = acc[mi][ni][r] + bv;
                size_t off;
                if (MODE == 0) {
                    off = (size_t)row * N + col;
                } else {
                    int b = row >> 11, s = row & (Sc - 1); // S = 2048
                    int h = col >> 6, dh = col & (DHc - 1);
                    if (MODE == 1)
                        off = (((size_t)(b * Hc + h) * Sc + s) << 6) + dh;
                    else
                        off = (((size_t)(b * Hc + h) * DHc + dh) << 11) + s;
                }
                out[off] = (TOUT)v;
            }
        }
    }
}

// ---------------------------------------------------------------------------
// Flash-style causal attention, v5 (REVERTED to the round-2 measured 64us
// version; v6's Ps re-swizzle + per-tile msk pipeline regressed).
// Double-buffered direct-to-LDS pipeline, one barrier per tile:
//   STAGE(buf^1, t+1) ; compute(buf) ; asm vmcnt(0) ; s_barrier
// Block = q-tile pair (qt, 15-p): every block does exactly 34 tile-iters;
// grid 512 = exactly 2 blocks/CU. LDS 59392B; launch_bounds(256,2).
// Q,K: [B,H,S,Dh] bf16; Vt: [B,H,Dh,S] bf16; mask: [B,S] int32
// ---------------------------------------------------------------------------
static constexpr int LPP = 72; // Ps padded row stride (elements)
static constexpr float CEXP = 1.4426950408889634f / 4096.0f; // log2(e)/Dh^2

__global__ __launch_bounds__(256, 2) void attn_fwd(const bf16* __restrict__ Q,
                                                   const bf16* __restrict__ K,
                                                   const bf16* __restrict__ Vt,
                                                   const int* __restrict__ mask,
                                                   bf16* __restrict__ Ctx) {
    __shared__ alignas(16) bf16 Ks[2][64 * 64];   // [buf][row*64+g*8] swizzled
    __shared__ alignas(16) bf16 Vs[2][64 * 64];   // [buf][dh*64+g*8] swizzled
    __shared__ alignas(16) bf16 Ps[4][32 * LPP];  // per-wave P[q][key]
    __shared__ alignas(16) float msk_all[Sc];     // whole pad-mask row, once

    const int tid = threadIdx.x;
    const int wave = tid >> 6, lane = tid & 63;
    const int quad = lane >> 4, l16 = lane & 15;
    // grid (8,64) = 512 blocks; XCD k gets bh in [8k,8k+8) x all 8 pair-ids
    const int id = blockIdx.y * 8 + blockIdx.x;
    const int sw = (id & 7) * 64 + (id >> 3);
    const int bh = sw >> 3, p = sw & 7;
    const int b = bh >> 4, h = bh & 15;

    // ---- pad mask -> float, whole row, once per block (8 elems/thread)
    {
        const int i = tid * 8;
        int4 m0 = *(const int4*)&mask[b * Sc + i];
        int4 m1 = *(const int4*)&mask[b * Sc + i + 4];
        f32x4 f0 = {m0.x ? 0.f : -1e30f, m0.y ? 0.f : -1e30f,
                    m0.z ? 0.f : -1e30f, m0.w ? 0.f : -1e30f};
        f32x4 f1 = {m1.x ? 0.f : -1e30f, m1.y ? 0.f : -1e30f,
                    m1.z ? 0.f : -1e30f, m1.w ? 0.f : -1e30f};
        *(f32x4*)&msk_all[i] = f0;
        *(f32x4*)&msk_all[i + 4] = f1;
    }

    // ---- staging geometry (both-sides swizzle, rule #21)
    const int swz = ((lane & 7) ^ (lane >> 3)) << 4;        // source byte XOR
    const int rA = wave * 16 + (lane >> 3);                  // local row, j=0
    const char* gK0 = (const char*)K + (size_t)bh * Sc * (DHc * 2)
                    + (size_t)rA * 128 + swz;
    const char* gV0 = (const char*)Vt + (size_t)bh * DHc * (Sc * 2)
                    + (size_t)rA * (Sc * 2) + swz;
    bf16* lK0 = &Ks[0][(wave * 16) * 64];
    bf16* lV0 = &Vs[0][(wave * 16) * 64];

    // read-side swizzled granule offsets (elements)
    const int m7 = l16 & 7;
    const int gsw0 = ((0 + quad) ^ m7) * 8;
    const int gsw1 = ((4 + quad) ^ m7) * 8;

#define STAGE(BUF, KB)                                                        \
    do {                                                                      \
        load_lds16((const bf16*)(gK0 + (size_t)(KB) * 128),                   \
                   lK0 + (BUF) * (64 * 64));                                  \
        load_lds16((const bf16*)(gK0 + (size_t)(KB) * 128 + 1024),            \
                   lK0 + (BUF) * (64 * 64) + 8 * 64);                         \
        load_lds16((const bf16*)(gV0 + (size_t)(KB) * 2),                     \
                   lV0 + (BUF) * (64 * 64));                                  \
        load_lds16((const bf16*)(gV0 + (size_t)(KB) * 2 + 8 * 4096),          \
                   lV0 + (BUF) * (64 * 64) + 8 * 64);                         \
    } while (0)

    // ---- two q-tile passes: heavy (15-p) then light (p); 34 tiles total
#pragma unroll 1
    for (int pass = 0; pass < 2; ++pass) {
        const int qt = pass ? p : 15 - p;
        const int qr0 = qt * 128 + wave * 32;
        const int qmax = qr0 + 31;

        // Q fragments (B-operand of S^T): n=q=l16, k=dh=quad*8+j
        bf16x8 bq[2][2];
#pragma unroll
        for (int mt = 0; mt < 2; ++mt) {
            const size_t qoff = ((size_t)bh * Sc + qr0 + mt * 16 + l16) * DHc;
            bq[mt][0] = *(const bf16x8*)&Q[qoff + quad * 8];
            bq[mt][1] = *(const bf16x8*)&Q[qoff + 32 + quad * 8];
        }

        f32x4 accO[2][4];
#pragma unroll
        for (int mt = 0; mt < 2; ++mt)
#pragma unroll
            for (int oi = 0; oi < 4; ++oi) accO[mt][oi] = (f32x4){0.f, 0.f, 0.f, 0.f};
        float l_part[2] = {0.f, 0.f};

        const int nkt = 2 * qt + 2;              // causal: k-tiles 0..(2qt+1)
        STAGE(0, 0);
        __syncthreads();                         // drains vmcnt+lgkmcnt; tile 0 ready
        int cur = 0;
#pragma unroll 1
        for (int kt = 0; kt < nkt; ++kt) {
            const int kb = kt * 64;
            if (kt + 1 < nkt) STAGE(cur ^ 1, kb + 64);   // issue next tile
            if (kb <= qmax) {                            // wave-uniform skip
                const bf16* Kb_ = &Ks[cur][0];
                const bf16* Vb_ = &Vs[cur][0];

                // S^T = K Q^T : A-frag = K rows (m=key), B-frag = bq (n=q)
                f32x4 st[2][4];
                __builtin_amdgcn_s_setprio(1);
#pragma unroll
                for (int kti = 0; kti < 4; ++kti) {
                    bf16x8 ak0 = *(const bf16x8*)&Kb_[(kti * 16 + l16) * 64 + gsw0];
                    bf16x8 ak1 = *(const bf16x8*)&Kb_[(kti * 16 + l16) * 64 + gsw1];
#pragma unroll
                    for (int mt = 0; mt < 2; ++mt) {
                        f32x4 z = {0.f, 0.f, 0.f, 0.f};
                        z = MFMA(ak0, bq[mt][0], z);
                        z = MFMA(ak1, bq[mt][1], z);
                        st[mt][kti] = z;
                    }
                }
                __builtin_amdgcn_s_setprio(0);

                // softmax numerator in exp2 domain (shift=0); packed P store.
#define SM_TILE(DIAG)                                                          \
                _Pragma("unroll")                                              \
                for (int mt = 0; mt < 2; ++mt) {                               \
                    _Pragma("unroll")                                          \
                    for (int kti = 0; kti < 4; ++kti) {                        \
                        const f32x4 mkv =                                      \
                            *(const f32x4*)&msk_all[kb + kti * 16 + quad * 4]; \
                        const int cbase =                                      \
                            kb + kti * 16 + quad * 4 - (qr0 + mt * 16);        \
                        bf16x4 pv;                                             \
                        _Pragma("unroll")                                      \
                        for (int r = 0; r < 4; ++r) {                          \
                            float s = st[mt][kti][r] * CEXP + mkv[r];          \
                            if (DIAG) s = (cbase + r > l16) ? -1e30f : s;      \
                            float p_ = __builtin_amdgcn_exp2f(s);              \
                            l_part[mt] += p_;                                  \
                            pv[r] = (bf16)p_;                                  \
                        }                                                      \
                        *(bf16x4*)&Ps[wave][(mt * 16 + l16) * LPP +            \
                                            kti * 16 + quad * 4] = pv;         \
                    }                                                          \
                }
                if (kb + 63 > qr0) { SM_TILE(1) } else { SM_TILE(0) }
#undef SM_TILE
                // Ps[wave] wave-private: per-wave DS ordering suffices

                // O += P V : A = Ps rows (m=q), B = Vs rows (n=dh)
                __builtin_amdgcn_s_setprio(1);
#pragma unroll
                for (int kk = 0; kk < 2; ++kk) {
                    bf16x8 ap0 = *(const bf16x8*)&Ps[wave][(l16) * LPP + kk * 32 + quad * 8];
                    bf16x8 ap1 = *(const bf16x8*)&Ps[wave][(16 + l16) * LPP + kk * 32 + quad * 8];
                    const int vg = kk ? gsw1 : gsw0;
#pragma unroll
                    for (int oi = 0; oi < 4; ++oi) {
                        bf16x8 bv = *(const bf16x8*)&Vb_[(oi * 16 + l16) * 64 + vg];
                        accO[0][oi] = MFMA(ap0, bv, accO[0][oi]);
                        accO[1][oi] = MFMA(ap1, bv, accO[1][oi]);
                    }
                }
                __builtin_amdgcn_s_setprio(0);
            }
            // wait own DMA, then publish across waves; next tile ready
            asm volatile("s_waitcnt vmcnt(0)" ::: "memory");
            __builtin_amdgcn_s_barrier();
            __builtin_amdgcn_sched_barrier(0);   // pin reads after barrier
            cur ^= 1;
        }

        // epilogue: finish l (sum over quads), redistribute, store
        float lvi[2][4];
#pragma unroll
        for (int mt = 0; mt < 2; ++mt) {
            float l = l_part[mt];
            l += __shfl_xor(l, 16);
            l += __shfl_xor(l, 32);              // lane holds l for q=l16
#pragma unroll
            for (int r = 0; r < 4; ++r)
                lvi[mt][r] = __builtin_amdgcn_rcpf(__shfl(l, quad * 4 + r));
        }
#pragma unroll
        for (int mt = 0; mt < 2; ++mt)
#pragma unroll
            for (int oi = 0; oi < 4; ++oi)
#pragma unroll
                for (int r = 0; r < 4; ++r) {
                    int s = qr0 + mt * 16 + quad * 4 + r;
                    int dh = oi * 16 + l16;
                    float v = accO[mt][oi][r] * lvi[mt][r];
                    Ctx[((size_t)b * Sc + s) * Dc + h * DHc + dh] = (bf16)v;
                }
    }
#undef STAGE
}

// ---------------------------------------------------------------------------
extern "C" void kernel_launch(void* const* d_in, const int* in_sizes, int n_in,
                              void* d_out, int out_size, void* d_ws, size_t ws_size,
                              hipStream_t stream) {
    const float* query = (const float*)d_in[0];
    const float* key_i = (const float*)d_in[1];
    const float* value = (const float*)d_in[2];
    const int* mask    = (const int*)d_in[3];
    const float* W_q = (const float*)d_in[4];
    const float* b_q = (const float*)d_in[5];
    const float* W_k = (const float*)d_in[6];
    const float* b_k = (const float*)d_in[7];
    const float* W_v = (const float*)d_in[8];
    const float* b_v = (const float*)d_in[9];
    const float* W_o = (const float*)d_in[10];
    const float* b_o = (const float*)d_in[11];
    float* out = (float*)d_out;

    const size_t MB = 1024 * 1024;
    const size_t NEED = 72 * MB;
    if (ws_size < NEED) {
        fill_diag<<<(out_size + 255) / 256, 256, 0, stream>>>(out, out_size);
        return;
    }

    char* ws = (char*)d_ws;
    bf16* WtQ = (bf16*)(ws + 0 * MB);   // 2 MB each
    bf16* WtK = (bf16*)(ws + 2 * MB);
    bf16* WtV = (bf16*)(ws + 4 * MB);
    bf16* WtO = (bf16*)(ws + 6 * MB);
    bf16* Xin = (bf16*)(ws + 8 * MB);   // 16 MB staging, serially reused
    bf16* Ctx = (bf16*)(ws + 8 * MB);   // aliases Xin (dead by attention time)
    bf16* Qb  = (bf16*)(ws + 24 * MB);  // [B,H,S,Dh]
    bf16* Kb  = (bf16*)(ws + 40 * MB);  // [B,H,S,Dh]
    bf16* Vtb = (bf16*)(ws + 56 * MB);  // [B,H,Dh,S]

    transpose4<<<dim3(32, 32, 4), dim3(32, 8), 0, stream>>>(
        W_q, W_k, W_v, W_o, WtQ, WtK, WtV, WtO);

    const int ncv = Mc * Dc;            // 8.39M elems, /8 per thread
    dim3 gg(Dc / 128, Mc / 128);        // (8, 64)

    cvt_bf16<<<ncv / (256 * 8), 256, 0, stream>>>(query, Xin, ncv);
    gemm_bt<1, bf16><<<gg, 256, 0, stream>>>(Xin, WtQ, b_q, Qb, Mc, Dc, Dc);
    cvt_bf16<<<ncv / (256 * 8), 256, 0, stream>>>(key_i, Xin, ncv);
    gemm_bt<1, bf16><<<gg, 256, 0, stream>>>(Xin, WtK, b_k, Kb, Mc, Dc, Dc);
    cvt_bf16<<<ncv / (256 * 8), 256, 0, stream>>>(value, Xin, ncv);
    gemm_bt<2, bf16><<<gg, 256, 0, stream>>>(Xin, WtV, b_v, Vtb, Mc, Dc, Dc);

    attn_fwd<<<dim3(8, Bc * Hc), 256, 0, stream>>>(Qb, Kb, Vtb, mask, Ctx);

    gemm_bt<0, float><<<gg, 256, 0, stream>>>(Ctx, WtO, b_o, out, Mc, Dc, Dc);
}